// Round 1
// baseline (192.869 us; speedup 1.0000x reference)
//
#include <hip/hip_runtime.h>
#include <hip/hip_bf16.h>

// Exploits: (1) looper == sigmoid(3.0) exactly -> loop runs exactly 1 extra
// iteration -> two long_conv applications total, lc_* inputs unused.
// (2) key only needs 32x32 sampled conv outputs; final output only needs
// 128x128 sampled positions of the 4093^2 transposed-conv -> compute sparsely,
// never materialize out1/out2.
//
// Shapes: input [3,1024,1024]; out1 = convT(x,kern1) [3,2047,2047];
// out2 = convT(out1,kern2) [3,4093,4093]; output = sigmoid(out2) sampled
// at (i*4093//128, j*4093//128) -> [3,128,128] fp32.
// kern layout (in,out,kh,kw): cin*75 + cout*25 + kh*5 + kw.
// convT tap: out[o,oy,ox] = sum_{ci,kh,kw} x[ci,(oy+2-kh)/2,(ox+2-kw)/2]*w[ci,o,kh,kw]
// (valid when numerator even and index in range; zero otherwise).

__device__ __forceinline__ float sigmoidf_(float z) {
    return 1.0f / (1.0f + expf(-z));
}

// ---- K1: key1[c*1024 + i*32 + j] = sigmoid(conv2d_s2(2*in-1) at (ri[i],ci[j])) ----
__global__ void k_key1(const float* __restrict__ in, const float* __restrict__ w,
                       const float* __restrict__ b, float* __restrict__ key) {
    __shared__ float sw[225];
    __shared__ float sb[3];
    int t = threadIdx.x;
    if (t < 225) sw[t] = w[t];
    if (t < 3)   sb[t] = b[t];
    __syncthreads();
    int g  = blockIdx.x * blockDim.x + t;   // 0..1023
    int ii = g >> 5, jj = g & 31;
    int y0 = 2 * ((ii * 510) >> 5);         // 2 * (ii*510/32)
    int x0 = 2 * ((jj * 510) >> 5);
    float acc0 = sb[0], acc1 = sb[1], acc2 = sb[2];
#pragma unroll
    for (int ci = 0; ci < 3; ++ci) {
        float xp[25];
#pragma unroll
        for (int u = 0; u < 5; ++u)
#pragma unroll
            for (int v = 0; v < 5; ++v)
                xp[u * 5 + v] = 2.0f * in[ci * 1048576 + (y0 + u) * 1024 + (x0 + v)] - 1.0f;
        float s0 = 0.f, s1 = 0.f, s2 = 0.f;
#pragma unroll
        for (int k = 0; k < 25; ++k) {
            s0 += xp[k] * sw[0 * 75 + ci * 25 + k];
            s1 += xp[k] * sw[1 * 75 + ci * 25 + k];
            s2 += xp[k] * sw[2 * 75 + ci * 25 + k];
        }
        acc0 += s0; acc1 += s1; acc2 += s2;
    }
    key[0 * 1024 + g] = sigmoidf_(acc0);
    key[1 * 1024 + g] = sigmoidf_(acc1);
    key[2 * 1024 + g] = sigmoidf_(acc2);
}

// ---- K2/K4: logits = keys@keyvec; att = softmax(logits); kern = values^T att ----
__global__ void k_att(const float* __restrict__ keyvec, const float* __restrict__ keys,
                      const float* __restrict__ values, float* __restrict__ kern) {
    __shared__ float slog[100];
    __shared__ float satt[100];
    int t = threadIdx.x;
    int lane = t & 63, wv = t >> 6;   // 4 waves
    float kv[48];
#pragma unroll
    for (int m = 0; m < 48; ++m) kv[m] = keyvec[m * 64 + lane];
    for (int n = wv; n < 100; n += 4) {
        const float* kr = keys + n * 3072;
        float s = 0.f;
#pragma unroll
        for (int m = 0; m < 48; ++m) s += kv[m] * kr[m * 64 + lane];
#pragma unroll
        for (int off = 32; off > 0; off >>= 1) s += __shfl_xor(s, off, 64);
        if (lane == 0) slog[n] = s;
    }
    __syncthreads();
    if (wv == 0) {
        float v1 = slog[lane];                                  // lane<64<100 ok
        float v2 = (lane + 64 < 100) ? slog[lane + 64] : -3.4e38f;
        float mx = fmaxf(v1, v2);
#pragma unroll
        for (int off = 32; off > 0; off >>= 1) mx = fmaxf(mx, __shfl_xor(mx, off, 64));
        float e1 = expf(v1 - mx);
        float e2 = (lane + 64 < 100) ? expf(v2 - mx) : 0.f;
        float s = e1 + e2;
#pragma unroll
        for (int off = 32; off > 0; off >>= 1) s += __shfl_xor(s, off, 64);
        float inv = 1.0f / s;
        satt[lane] = e1 * inv;
        if (lane + 64 < 100) satt[lane + 64] = e2 * inv;
    }
    __syncthreads();
    if (t < 225) {
        float s = 0.f;
        for (int n = 0; n < 100; ++n) s += values[n * 225 + t] * satt[n];
        kern[t] = s;
    }
}

// ---- K3: key2 = sigmoid(conv2d_s2(convT(x,kern1)) at sampled positions) ----
// Sample rows are even (2*ri2) -> all parities compile-time; x zero-padded.
__global__ void k_key2(const float* __restrict__ in, const float* __restrict__ w,
                       const float* __restrict__ b, const float* __restrict__ k1,
                       float* __restrict__ key) {
    __shared__ float sw[225], sk1[225], sb[3];
    int t = threadIdx.x;
    if (t < 225) { sw[t] = w[t]; sk1[t] = k1[t]; }
    if (t < 3)   sb[t] = b[t];
    __syncthreads();
    int g  = blockIdx.x * blockDim.x + t;   // 0..1023
    int ii = g >> 5, jj = g & 31;
    int iy0 = (ii * 1022) >> 5;             // conv pos ri2; out1 rows 2*iy0..+4
    int ix0 = (jj * 1022) >> 5;
    float o1[75];                           // out1 patch [cm][u][v]
#pragma unroll
    for (int q = 0; q < 75; ++q) o1[q] = 0.f;
#pragma unroll
    for (int ci = 0; ci < 3; ++ci) {
        float xp[25];                       // x rows iy0-1..iy0+3, zero-padded
#pragma unroll
        for (int a = 0; a < 5; ++a) {
            int iy = iy0 - 1 + a;
            bool ry = (unsigned)iy < 1024u;
#pragma unroll
            for (int bb = 0; bb < 5; ++bb) {
                int ix = ix0 - 1 + bb;
                bool ok = ry && ((unsigned)ix < 1024u);
                xp[a * 5 + bb] = ok ? (2.0f * in[ci * 1048576 + iy * 1024 + ix] - 1.0f) : 0.f;
            }
        }
#pragma unroll
        for (int u = 0; u < 5; ++u)
#pragma unroll
            for (int c = 0; c < 5; ++c) {
                if ((u ^ c) & 1) continue;          // folds at compile time
                const int a = (u + 4 - c) >> 1;
#pragma unroll
                for (int v = 0; v < 5; ++v)
#pragma unroll
                    for (int d = 0; d < 5; ++d) {
                        if ((v ^ d) & 1) continue;
                        const int bb = (v + 4 - d) >> 1;
                        float xv = xp[a * 5 + bb];
#pragma unroll
                        for (int cm = 0; cm < 3; ++cm)
                            o1[cm * 25 + u * 5 + v] += xv * sk1[ci * 75 + cm * 25 + c * 5 + d];
                    }
            }
    }
    float acc0 = sb[0], acc1 = sb[1], acc2 = sb[2];
#pragma unroll
    for (int q = 0; q < 75; ++q) {
        acc0 += o1[q] * sw[0 * 75 + q];
        acc1 += o1[q] * sw[1 * 75 + q];
        acc2 += o1[q] * sw[2 * 75 + q];
    }
    key[0 * 1024 + g] = sigmoidf_(acc0);
    key[1 * 1024 + g] = sigmoidf_(acc1);
    key[2 * 1024 + g] = sigmoidf_(acc2);
}

// ---- K5: out[c,i,j] = sigmoid(out2[c, i*4093/128, j*4093/128]) ----
__global__ void k_final(const float* __restrict__ in, const float* __restrict__ k1,
                        const float* __restrict__ k2, float* __restrict__ out) {
    __shared__ float sk1[225], sk2[225];
    int t = threadIdx.x;
    for (int q = t; q < 225; q += blockDim.x) { sk1[q] = k1[q]; sk2[q] = k2[q]; }
    __syncthreads();
    int T = blockIdx.x * blockDim.x + t;    // 0..16383
    int i = T >> 7, j = T & 127;
    int R = (i * 4093) >> 7;                // wave-uniform (i uniform per wave)
    int C = (j * 4093) >> 7;
    float acc0 = 0.f, acc1 = 0.f, acc2 = 0.f;
    for (int a = 0; a < 5; ++a) {
        int ty = R + 2 - a;
        if (ty & 1) continue;
        int oy = ty >> 1;
        if ((unsigned)oy >= 2047u) continue;          // handles R=0 phantom exactly
        for (int bb = 0; bb < 5; ++bb) {
            int tx = C + 2 - bb;
            if (tx & 1) continue;
            int ox = tx >> 1;
            if ((unsigned)ox >= 2047u) continue;
            // out1[cm][oy][ox] on the fly
            float p0 = 0.f, p1 = 0.f, p2 = 0.f;
            for (int c = 0; c < 5; ++c) {
                int t2 = oy + 2 - c;
                if (t2 & 1) continue;
                int iy = t2 >> 1;
                if ((unsigned)iy >= 1024u) continue;
                for (int d = 0; d < 5; ++d) {
                    int t3 = ox + 2 - d;
                    if (t3 & 1) continue;
                    int ix = t3 >> 1;
                    if ((unsigned)ix >= 1024u) continue;
                    int xoff = iy * 1024 + ix;
                    float xv0 = 2.0f * in[xoff] - 1.0f;
                    float xv1 = 2.0f * in[1048576 + xoff] - 1.0f;
                    float xv2 = 2.0f * in[2097152 + xoff] - 1.0f;
                    int kb = c * 5 + d;
                    p0 += xv0 * sk1[kb] + xv1 * sk1[75 + kb] + xv2 * sk1[150 + kb];
                    p1 += xv0 * sk1[25 + kb] + xv1 * sk1[100 + kb] + xv2 * sk1[175 + kb];
                    p2 += xv0 * sk1[50 + kb] + xv1 * sk1[125 + kb] + xv2 * sk1[200 + kb];
                }
            }
            int ab = a * 5 + bb;
            acc0 += p0 * sk2[ab]       + p1 * sk2[75 + ab]  + p2 * sk2[150 + ab];
            acc1 += p0 * sk2[25 + ab]  + p1 * sk2[100 + ab] + p2 * sk2[175 + ab];
            acc2 += p0 * sk2[50 + ab]  + p1 * sk2[125 + ab] + p2 * sk2[200 + ab];
        }
    }
    out[0 * 16384 + T] = sigmoidf_(acc0);
    out[1 * 16384 + T] = sigmoidf_(acc1);
    out[2 * 16384 + T] = sigmoidf_(acc2);
}

extern "C" void kernel_launch(void* const* d_in, const int* in_sizes, int n_in,
                              void* d_out, int out_size, void* d_ws, size_t ws_size,
                              hipStream_t stream) {
    const float* in   = (const float*)d_in[0];   // [3,1024,1024]
    const float* cw   = (const float*)d_in[1];   // [3,3,5,5]
    const float* cb   = (const float*)d_in[2];   // [3]
    const float* keys = (const float*)d_in[3];   // [100,3072]
    const float* vals = (const float*)d_in[4];   // [100,225]
    // d_in[5..8] (lc_*) provably unused: looper == 3.0 exactly.
    float* out = (float*)d_out;                  // [3,128,128] fp32
    float* ws  = (float*)d_ws;
    float* key1  = ws;            // 3072
    float* kern1 = ws + 4096;     // 225
    float* key2  = ws + 8192;     // 3072
    float* kern2 = ws + 12288;    // 225

    k_key1 <<<4,   256, 0, stream>>>(in, cw, cb, key1);
    k_att  <<<1,   256, 0, stream>>>(key1, keys, vals, kern1);
    k_key2 <<<4,   256, 0, stream>>>(in, cw, cb, kern1, key2);
    k_att  <<<1,   256, 0, stream>>>(key2, keys, vals, kern2);
    k_final<<<256, 64,  0, stream>>>(in, kern1, kern2, out);
}

// Round 2
// 127.942 us; speedup vs baseline: 1.5075x; 1.5075x over previous
//
#include <hip/hip_runtime.h>
#include <hip/hip_bf16.h>

// Structure (see round-0 notes): looper == sigmoid(3.0) exactly -> exactly two
// long_conv applications; lc_* inputs unused. All stages computed sparsely:
//   k_key (x2): 32x32 sampled stride-2 conv outputs, one WAVE per sample
//   k_logits:   keys[100,3072] @ key  -> one block per row
//   k_mix:      softmax + values-mix -> kern[225]; stage1 also builds the
//               composite conv(convT(.)) weights w_eff[3][75] (linear map)
//   k_final:    128x128 sampled positions of the 4093^2 output (unchanged)
// Weight layouts: cw/w_eff: [co*75 + ci*25 + r*5 + c]; kern: [ci*75+cm*25+..].

__device__ __forceinline__ float sigmoidf_(float z) {
    return 1.0f / (1.0f + expf(-z));
}

// ---- unified sampled-conv key kernel: one wave per sample (1024 waves) ----
// base_y = dbl ? 2*((ii*mul)>>5) : ((ii*mul)>>5)-1   (key1: mul=510,dbl=1;
// key2: mul=1022,dbl=0).  Always zero-pad out-of-range (only hits key2 edges).
__global__ void k_key(const float* __restrict__ in, const float* __restrict__ w,
                      const float* __restrict__ b, float* __restrict__ key,
                      int mul, int dbl) {
    __shared__ float sw[225];
    __shared__ float sb[3];
    int t = threadIdx.x;
    if (t < 225) sw[t] = w[t];
    if (t < 3)   sb[t] = b[t];
    __syncthreads();
    int wave = blockIdx.x * 4 + (t >> 6);   // 0..1023 = sample id
    int lane = t & 63;
    int ii = wave >> 5, jj = wave & 31;
    int qy = (ii * mul) >> 5, qx = (jj * mul) >> 5;
    int by = dbl ? 2 * qy : qy - 1;
    int bx = dbl ? 2 * qx : qx - 1;

    // value l in [0,75): ci=l/25, r=(l%25)/5, c=l%5 ; lane handles l=lane (+64)
    float p0 = 0.f, p1 = 0.f, p2 = 0.f;
    {
        int l = lane;                        // < 64 < 75: always valid
        int ci = l / 25, rm = l % 25, r = rm / 5, cc = rm % 5;
        int y = by + r, x = bx + cc;
        float xv = 0.f;
        if ((unsigned)y < 1024u && (unsigned)x < 1024u)
            xv = 2.0f * in[ci * 1048576 + y * 1024 + x] - 1.0f;
        p0 = xv * sw[l]; p1 = xv * sw[75 + l]; p2 = xv * sw[150 + l];
    }
    if (lane < 11) {
        int l = lane + 64;
        int ci = l / 25, rm = l % 25, r = rm / 5, cc = rm % 5;
        int y = by + r, x = bx + cc;
        float xv = 0.f;
        if ((unsigned)y < 1024u && (unsigned)x < 1024u)
            xv = 2.0f * in[ci * 1048576 + y * 1024 + x] - 1.0f;
        p0 += xv * sw[l]; p1 += xv * sw[75 + l]; p2 += xv * sw[150 + l];
    }
#pragma unroll
    for (int off = 32; off > 0; off >>= 1) {
        p0 += __shfl_xor(p0, off, 64);
        p1 += __shfl_xor(p1, off, 64);
        p2 += __shfl_xor(p2, off, 64);
    }
    if (lane == 0) {
        key[0 * 1024 + wave] = sigmoidf_(p0 + sb[0]);
        key[1 * 1024 + wave] = sigmoidf_(p1 + sb[1]);
        key[2 * 1024 + wave] = sigmoidf_(p2 + sb[2]);
    }
}

// ---- logits[n] = keys[n,:] . keyvec  (one block per n) ----
__global__ void k_logits(const float* __restrict__ keyvec, const float* __restrict__ keys,
                         float* __restrict__ logits) {
    __shared__ float red[4];
    int n = blockIdx.x, t = threadIdx.x;
    const float* kr = keys + n * 3072;
    float s = 0.f;
#pragma unroll
    for (int m = 0; m < 12; ++m) s += kr[m * 256 + t] * keyvec[m * 256 + t];
#pragma unroll
    for (int off = 32; off > 0; off >>= 1) s += __shfl_xor(s, off, 64);
    if ((t & 63) == 0) red[t >> 6] = s;
    __syncthreads();
    if (t == 0) logits[n] = red[0] + red[1] + red[2] + red[3];
}

// ---- softmax(logits) -> kern = values^T att ; stage1: also w_eff ----
// w_eff[co][ci][a][bb] = sum_{(u,c):u=c+2a-4} sum_{(v,d):v=d+2bb-4} sum_cm
//                        kern[ci*75+cm*25+c*5+d] * cw[co*75+cm*25+u*5+v]
__global__ void k_mix(const float* __restrict__ logits, const float* __restrict__ values,
                      const float* __restrict__ cw, float* __restrict__ kern,
                      float* __restrict__ w_eff, int do_weff) {
    __shared__ float satt[100];
    __shared__ float skern[225];
    int t = threadIdx.x;
    int lane = t & 63, wv = t >> 6;
    if (wv == 0) {
        float v1 = logits[lane];
        float v2 = (lane + 64 < 100) ? logits[lane + 64] : -3.4e38f;
        float mx = fmaxf(v1, v2);
#pragma unroll
        for (int off = 32; off > 0; off >>= 1) mx = fmaxf(mx, __shfl_xor(mx, off, 64));
        float e1 = expf(v1 - mx);
        float e2 = (lane + 64 < 100) ? expf(v2 - mx) : 0.f;
        float s = e1 + e2;
#pragma unroll
        for (int off = 32; off > 0; off >>= 1) s += __shfl_xor(s, off, 64);
        float inv = 1.0f / s;
        satt[lane] = e1 * inv;
        if (lane + 64 < 100) satt[lane + 64] = e2 * inv;
    }
    __syncthreads();
    if (t < 225) {
        float s = 0.f;
        for (int n = 0; n < 100; ++n) s += values[n * 225 + t] * satt[n];
        skern[t] = s;
        kern[t] = s;
    }
    __syncthreads();
    if (do_weff && t < 225) {
        int co = t / 75, rem = t % 75, ci = rem / 25, a = (rem % 25) / 5, bb = rem % 5;
        float s = 0.f;
#pragma unroll
        for (int c = 0; c < 5; ++c) {
            int u = c + 2 * a - 4;
            if ((unsigned)u >= 5u) continue;
#pragma unroll
            for (int d = 0; d < 5; ++d) {
                int v = d + 2 * bb - 4;
                if ((unsigned)v >= 5u) continue;
#pragma unroll
                for (int cm = 0; cm < 3; ++cm)
                    s += skern[ci * 75 + cm * 25 + c * 5 + d] * cw[co * 75 + cm * 25 + u * 5 + v];
            }
        }
        w_eff[t] = s;
    }
}

// ---- K5: out[c,i,j] = sigmoid(out2[c, i*4093/128, j*4093/128]) (unchanged) ----
__global__ void k_final(const float* __restrict__ in, const float* __restrict__ k1,
                        const float* __restrict__ k2, float* __restrict__ out) {
    __shared__ float sk1[225], sk2[225];
    int t = threadIdx.x;
    for (int q = t; q < 225; q += blockDim.x) { sk1[q] = k1[q]; sk2[q] = k2[q]; }
    __syncthreads();
    int T = blockIdx.x * blockDim.x + t;    // 0..16383
    int i = T >> 7, j = T & 127;
    int R = (i * 4093) >> 7;
    int C = (j * 4093) >> 7;
    float acc0 = 0.f, acc1 = 0.f, acc2 = 0.f;
    for (int a = 0; a < 5; ++a) {
        int ty = R + 2 - a;
        if (ty & 1) continue;
        int oy = ty >> 1;
        if ((unsigned)oy >= 2047u) continue;
        for (int bb = 0; bb < 5; ++bb) {
            int tx = C + 2 - bb;
            if (tx & 1) continue;
            int ox = tx >> 1;
            if ((unsigned)ox >= 2047u) continue;
            float p0 = 0.f, p1 = 0.f, p2 = 0.f;
            for (int c = 0; c < 5; ++c) {
                int t2 = oy + 2 - c;
                if (t2 & 1) continue;
                int iy = t2 >> 1;
                if ((unsigned)iy >= 1024u) continue;
                for (int d = 0; d < 5; ++d) {
                    int t3 = ox + 2 - d;
                    if (t3 & 1) continue;
                    int ix = t3 >> 1;
                    if ((unsigned)ix >= 1024u) continue;
                    int xoff = iy * 1024 + ix;
                    float xv0 = 2.0f * in[xoff] - 1.0f;
                    float xv1 = 2.0f * in[1048576 + xoff] - 1.0f;
                    float xv2 = 2.0f * in[2097152 + xoff] - 1.0f;
                    int kb = c * 5 + d;
                    p0 += xv0 * sk1[kb] + xv1 * sk1[75 + kb] + xv2 * sk1[150 + kb];
                    p1 += xv0 * sk1[25 + kb] + xv1 * sk1[100 + kb] + xv2 * sk1[175 + kb];
                    p2 += xv0 * sk1[50 + kb] + xv1 * sk1[125 + kb] + xv2 * sk1[200 + kb];
                }
            }
            int ab = a * 5 + bb;
            acc0 += p0 * sk2[ab]       + p1 * sk2[75 + ab]  + p2 * sk2[150 + ab];
            acc1 += p0 * sk2[25 + ab]  + p1 * sk2[100 + ab] + p2 * sk2[175 + ab];
            acc2 += p0 * sk2[50 + ab]  + p1 * sk2[125 + ab] + p2 * sk2[200 + ab];
        }
    }
    out[0 * 16384 + T] = sigmoidf_(acc0);
    out[1 * 16384 + T] = sigmoidf_(acc1);
    out[2 * 16384 + T] = sigmoidf_(acc2);
}

extern "C" void kernel_launch(void* const* d_in, const int* in_sizes, int n_in,
                              void* d_out, int out_size, void* d_ws, size_t ws_size,
                              hipStream_t stream) {
    const float* in   = (const float*)d_in[0];   // [3,1024,1024]
    const float* cw   = (const float*)d_in[1];   // [3,3,5,5]
    const float* cb   = (const float*)d_in[2];   // [3]
    const float* keys = (const float*)d_in[3];   // [100,3072]
    const float* vals = (const float*)d_in[4];   // [100,225]
    float* out = (float*)d_out;                  // [3,128,128] fp32
    float* ws  = (float*)d_ws;
    float* key1   = ws;             // 3072
    float* logit1 = ws + 3072;      // 100
    float* kern1  = ws + 3200;      // 225
    float* w_eff  = ws + 3456;      // 225
    float* key2   = ws + 4096;      // 3072
    float* logit2 = ws + 7168;      // 100
    float* kern2  = ws + 7296;      // 225

    k_key   <<<256, 256, 0, stream>>>(in, cw, cb, key1, 510, 1);
    k_logits<<<100, 256, 0, stream>>>(key1, keys, logit1);
    k_mix   <<<1,   256, 0, stream>>>(logit1, vals, cw, kern1, w_eff, 1);
    k_key   <<<256, 256, 0, stream>>>(in, w_eff, cb, key2, 1022, 0);
    k_logits<<<100, 256, 0, stream>>>(key2, keys, logit2);
    k_mix   <<<1,   256, 0, stream>>>(logit2, vals, cw, kern2, w_eff, 0);
    k_final <<<256, 64,  0, stream>>>(in, kern1, kern2, out);
}

// Round 3
// 121.654 us; speedup vs baseline: 1.5854x; 1.0517x over previous
//
#include <hip/hip_runtime.h>
#include <hip/hip_bf16.h>

// Structure: looper == sigmoid(3.0) exactly -> exactly two long_conv
// applications; lc_* inputs unused. All stages computed sparsely:
//   k_key (x2): 32x32 sampled stride-2 conv outputs, one WAVE per sample
//               (stage-2 uses composite conv(convT(.)) weights w_eff)
//   k_logits:   keys[100,3072] @ key -> one block per row
//   k_mix:      softmax + values-mix -> kern[225]; stage1 builds w_eff;
//               stage2 builds the composite stride-4 13x13 convT weights
//               W[3][3][13][13] + boundary-phantom corrections Wy/Wx/Wxy
//   k_final:    128x128 sampled positions of convT(convT(x,k1),k2) via the
//               composite kernel: <=4x4 contiguous input taps per pixel.
// Layouts: cw/w_eff/kern: [cin*75 + cout*25 + r*5 + c].
// Composite: out2[o,R,C] = sum_{ci,e,f} x[ci,iy,ix]*W[ci,o,e,f],
//   4iy = R+6-e, 4ix = C+6-f, e,f in [0,12].
//   W[ci,o,e,f] = sum_cm sum_{a+2c=e} sum_{b+2d=f} k1[ci,cm,c,d]*k2[cm,o,a,b]
// Clipping of the 2047^2 intermediate matters only at R==0 (pair a=4,c=1,
// iy=0) / C==0 (pair b=4,d=1, ix=0) among sampled pixels (max sampled
// R=4061 -> oy1<=2031<2047, high side unreachable). Corrections:
//   Wy[ci,o,f]  = sum_cm sum_{b+2d=f} k1[ci,cm,1,d]*k2[cm,o,4,b]
//   Wx[ci,o,e]  = sum_cm sum_{a+2c=e} k1[ci,cm,c,1]*k2[cm,o,a,4]
//   Wxy[ci,o]   = sum_cm k1[ci,cm,1,1]*k2[cm,o,4,4]
// acc_true = acc_naive - [R==0]*Y - [C==0]*X + [R==0&&C==0]*XY.

__device__ __forceinline__ float sigmoidf_(float z) {
    return 1.0f / (1.0f + expf(-z));
}

// ---- unified sampled-conv key kernel: one wave per sample (1024 waves) ----
__global__ void k_key(const float* __restrict__ in, const float* __restrict__ w,
                      const float* __restrict__ b, float* __restrict__ key,
                      int mul, int dbl) {
    __shared__ float sw[225];
    __shared__ float sb[3];
    int t = threadIdx.x;
    if (t < 225) sw[t] = w[t];
    if (t < 3)   sb[t] = b[t];
    __syncthreads();
    int wave = blockIdx.x * 4 + (t >> 6);   // 0..1023 = sample id
    int lane = t & 63;
    int ii = wave >> 5, jj = wave & 31;
    int qy = (ii * mul) >> 5, qx = (jj * mul) >> 5;
    int by = dbl ? 2 * qy : qy - 1;
    int bx = dbl ? 2 * qx : qx - 1;

    float p0 = 0.f, p1 = 0.f, p2 = 0.f;
    {
        int l = lane;                        // < 64 < 75: always valid
        int ci = l / 25, rm = l % 25, r = rm / 5, cc = rm % 5;
        int y = by + r, x = bx + cc;
        float xv = 0.f;
        if ((unsigned)y < 1024u && (unsigned)x < 1024u)
            xv = 2.0f * in[ci * 1048576 + y * 1024 + x] - 1.0f;
        p0 = xv * sw[l]; p1 = xv * sw[75 + l]; p2 = xv * sw[150 + l];
    }
    if (lane < 11) {
        int l = lane + 64;
        int ci = l / 25, rm = l % 25, r = rm / 5, cc = rm % 5;
        int y = by + r, x = bx + cc;
        float xv = 0.f;
        if ((unsigned)y < 1024u && (unsigned)x < 1024u)
            xv = 2.0f * in[ci * 1048576 + y * 1024 + x] - 1.0f;
        p0 += xv * sw[l]; p1 += xv * sw[75 + l]; p2 += xv * sw[150 + l];
    }
#pragma unroll
    for (int off = 32; off > 0; off >>= 1) {
        p0 += __shfl_xor(p0, off, 64);
        p1 += __shfl_xor(p1, off, 64);
        p2 += __shfl_xor(p2, off, 64);
    }
    if (lane == 0) {
        key[0 * 1024 + wave] = sigmoidf_(p0 + sb[0]);
        key[1 * 1024 + wave] = sigmoidf_(p1 + sb[1]);
        key[2 * 1024 + wave] = sigmoidf_(p2 + sb[2]);
    }
}

// ---- logits[n] = keys[n,:] . keyvec  (one block per n) ----
__global__ void k_logits(const float* __restrict__ keyvec, const float* __restrict__ keys,
                         float* __restrict__ logits) {
    __shared__ float red[4];
    int n = blockIdx.x, t = threadIdx.x;
    const float* kr = keys + n * 3072;
    float s = 0.f;
#pragma unroll
    for (int m = 0; m < 12; ++m) s += kr[m * 256 + t] * keyvec[m * 256 + t];
#pragma unroll
    for (int off = 32; off > 0; off >>= 1) s += __shfl_xor(s, off, 64);
    if ((t & 63) == 0) red[t >> 6] = s;
    __syncthreads();
    if (t == 0) logits[n] = red[0] + red[1] + red[2] + red[3];
}

// ---- softmax + values-mix -> kern; stage1: w_eff; stage2: composite W tables ----
__global__ void k_mix(const float* __restrict__ logits, const float* __restrict__ values,
                      const float* __restrict__ cw, const float* __restrict__ g_kern1,
                      float* __restrict__ kern, float* __restrict__ w_eff,
                      float* __restrict__ comp, int stage) {
    __shared__ float satt[100];
    __shared__ float skern[225];   // kern from THIS stage
    __shared__ float sk1[225];     // kern1 (stage 2 only)
    int t = threadIdx.x;
    int lane = t & 63, wv = t >> 6;
    if (wv == 0) {
        float v1 = logits[lane];
        float v2 = (lane + 64 < 100) ? logits[lane + 64] : -3.4e38f;
        float mx = fmaxf(v1, v2);
#pragma unroll
        for (int off = 32; off > 0; off >>= 1) mx = fmaxf(mx, __shfl_xor(mx, off, 64));
        float e1 = expf(v1 - mx);
        float e2 = (lane + 64 < 100) ? expf(v2 - mx) : 0.f;
        float s = e1 + e2;
#pragma unroll
        for (int off = 32; off > 0; off >>= 1) s += __shfl_xor(s, off, 64);
        float inv = 1.0f / s;
        satt[lane] = e1 * inv;
        if (lane + 64 < 100) satt[lane + 64] = e2 * inv;
    }
    if (stage == 2 && t < 225) sk1[t] = g_kern1[t];
    __syncthreads();
    if (t < 225) {
        float s = 0.f;
        for (int n = 0; n < 100; ++n) s += values[n * 225 + t] * satt[n];
        skern[t] = s;
        kern[t] = s;
    }
    __syncthreads();
    if (stage == 1) {
        // w_eff[co][ci][a][bb]: conv(convT(x,kern)) sampled-composite weights
        if (t < 225) {
            int co = t / 75, rem = t % 75, ci = rem / 25, a = (rem % 25) / 5, bb = rem % 5;
            float s = 0.f;
#pragma unroll
            for (int c = 0; c < 5; ++c) {
                int u = c + 2 * a - 4;
                if ((unsigned)u >= 5u) continue;
#pragma unroll
                for (int d = 0; d < 5; ++d) {
                    int v = d + 2 * bb - 4;
                    if ((unsigned)v >= 5u) continue;
#pragma unroll
                    for (int cm = 0; cm < 3; ++cm)
                        s += skern[ci * 75 + cm * 25 + c * 5 + d] * cw[co * 75 + cm * 25 + u * 5 + v];
                }
            }
            w_eff[t] = s;
        }
    } else {
        // composite stride-4 13x13 convT weights: skern = kern2, sk1 = kern1
        // comp layout: [0,1521) W[ci*3+o][e*13+f]; [1536,1653) Wy[(ci*3+o)*13+f];
        //              [1664,1781) Wx[(ci*3+o)*13+e]; [1792,1801) Wxy[ci*3+o]
        for (int idx = t; idx < 1521; idx += 256) {
            int ci = idx / 507, rem = idx % 507, o = rem / 169;
            int ef = rem % 169, e = ef / 13, f = ef % 13;
            float s = 0.f;
#pragma unroll
            for (int c = 0; c < 5; ++c) {
                int a = e - 2 * c;
                if ((unsigned)a >= 5u) continue;
#pragma unroll
                for (int d = 0; d < 5; ++d) {
                    int b2 = f - 2 * d;
                    if ((unsigned)b2 >= 5u) continue;
#pragma unroll
                    for (int cm = 0; cm < 3; ++cm)
                        s += sk1[ci * 75 + cm * 25 + c * 5 + d] * skern[cm * 75 + o * 25 + a * 5 + b2];
                }
            }
            comp[idx] = s;
        }
        if (t < 117) {   // Wy: phantom row (c=1 -> oy1=-1), a=4
            int ci = t / 39, o = (t % 39) / 13, f = t % 13;
            float s = 0.f;
#pragma unroll
            for (int d = 0; d < 5; ++d) {
                int b2 = f - 2 * d;
                if ((unsigned)b2 >= 5u) continue;
#pragma unroll
                for (int cm = 0; cm < 3; ++cm)
                    s += sk1[ci * 75 + cm * 25 + 1 * 5 + d] * skern[cm * 75 + o * 25 + 4 * 5 + b2];
            }
            comp[1536 + (ci * 3 + o) * 13 + f] = s;
        }
        if (t >= 128 && t < 245) {   // Wx: phantom col (d=1 -> ox1=-1), b=4
            int q = t - 128;
            int ci = q / 39, o = (q % 39) / 13, e = q % 13;
            float s = 0.f;
#pragma unroll
            for (int c = 0; c < 5; ++c) {
                int a = e - 2 * c;
                if ((unsigned)a >= 5u) continue;
#pragma unroll
                for (int cm = 0; cm < 3; ++cm)
                    s += sk1[ci * 75 + cm * 25 + c * 5 + 1] * skern[cm * 75 + o * 25 + a * 5 + 4];
            }
            comp[1664 + (ci * 3 + o) * 13 + e] = s;
        }
        if (t >= 246 && t < 255) {   // Wxy overlap
            int q = t - 246;
            int ci = q / 3, o = q % 3;
            float s = 0.f;
#pragma unroll
            for (int cm = 0; cm < 3; ++cm)
                s += sk1[ci * 75 + cm * 25 + 5 + 1] * skern[cm * 75 + o * 25 + 20 + 4];
            comp[1792 + ci * 3 + o] = s;
        }
    }
}

// ---- out[o,i,j] = sigmoid(composite-convT at (R,C)), <=4x4 contiguous taps ----
__global__ void k_final(const float* __restrict__ in, const float* __restrict__ comp,
                        float* __restrict__ out) {
    __shared__ float sW[1521];                 // [ci*3+o][e*13+f]
    __shared__ float sWy[117], sWx[117], sWxy[9];
    int t = threadIdx.x;                        // 0..127 ; blockIdx = row i
    for (int q = t; q < 1521; q += 128) sW[q] = comp[q];
    if (t < 117) { sWy[t] = comp[1536 + t]; sWx[t] = comp[1664 + t]; }
    if (t < 9)   sWxy[t] = comp[1792 + t];
    __syncthreads();
    int i = blockIdx.x, j = t;
    int R = (i * 4093) >> 7;
    int C = (j * 4093) >> 7;
    int ybase = (R + 6) >> 2, r0 = (R + 6) & 3, nk = (r0 == 0) ? 4 : 3;
    int xbase = (C + 6) >> 2, f0 = (C + 6) & 3, nl = (f0 == 0) ? 4 : 3;
    float a0 = 0.f, a1 = 0.f, a2 = 0.f;
    for (int k = 0; k < nk; ++k) {
        int iy = ybase - k;
        if ((unsigned)iy >= 1024u) continue;
        int e = r0 + 4 * k;
        for (int l = 0; l < nl; ++l) {
            int ix = xbase - l;
            if ((unsigned)ix >= 1024u) continue;
            int f = f0 + 4 * l;
            int off = iy * 1024 + ix;
            float x0 = 2.0f * in[off] - 1.0f;
            float x1 = 2.0f * in[1048576 + off] - 1.0f;
            float x2 = 2.0f * in[2097152 + off] - 1.0f;
            int wi = e * 13 + f;
            a0 += x0 * sW[wi] + x1 * sW[3 * 169 + wi] + x2 * sW[6 * 169 + wi];
            a1 += x0 * sW[169 + wi] + x1 * sW[4 * 169 + wi] + x2 * sW[7 * 169 + wi];
            a2 += x0 * sW[2 * 169 + wi] + x1 * sW[5 * 169 + wi] + x2 * sW[8 * 169 + wi];
        }
    }
    if (R == 0) {          // subtract phantom out1-row contribution (iy=0 row taps)
        for (int l = 0; l < nl; ++l) {
            int ix = xbase - l;
            if ((unsigned)ix >= 1024u) continue;
            int f = f0 + 4 * l;
            float x0 = 2.0f * in[ix] - 1.0f;
            float x1 = 2.0f * in[1048576 + ix] - 1.0f;
            float x2 = 2.0f * in[2097152 + ix] - 1.0f;
            a0 -= x0 * sWy[f] + x1 * sWy[3 * 13 + f] + x2 * sWy[6 * 13 + f];
            a1 -= x0 * sWy[13 + f] + x1 * sWy[4 * 13 + f] + x2 * sWy[7 * 13 + f];
            a2 -= x0 * sWy[2 * 13 + f] + x1 * sWy[5 * 13 + f] + x2 * sWy[8 * 13 + f];
        }
    }
    if (C == 0) {          // subtract phantom out1-col contribution (ix=0 col taps)
        for (int k = 0; k < nk; ++k) {
            int iy = ybase - k;
            if ((unsigned)iy >= 1024u) continue;
            int e = r0 + 4 * k;
            int off = iy * 1024;
            float x0 = 2.0f * in[off] - 1.0f;
            float x1 = 2.0f * in[1048576 + off] - 1.0f;
            float x2 = 2.0f * in[2097152 + off] - 1.0f;
            a0 -= x0 * sWx[e] + x1 * sWx[3 * 13 + e] + x2 * sWx[6 * 13 + e];
            a1 -= x0 * sWx[13 + e] + x1 * sWx[4 * 13 + e] + x2 * sWx[7 * 13 + e];
            a2 -= x0 * sWx[2 * 13 + e] + x1 * sWx[5 * 13 + e] + x2 * sWx[8 * 13 + e];
        }
    }
    if (R == 0 && C == 0) {   // add back doubly-removed overlap (x[*,0,0])
        float x0 = 2.0f * in[0] - 1.0f;
        float x1 = 2.0f * in[1048576] - 1.0f;
        float x2 = 2.0f * in[2097152] - 1.0f;
        a0 += x0 * sWxy[0] + x1 * sWxy[3] + x2 * sWxy[6];
        a1 += x0 * sWxy[1] + x1 * sWxy[4] + x2 * sWxy[7];
        a2 += x0 * sWxy[2] + x1 * sWxy[5] + x2 * sWxy[8];
    }
    int T = i * 128 + j;
    out[T]             = sigmoidf_(a0);
    out[16384 + T]     = sigmoidf_(a1);
    out[2 * 16384 + T] = sigmoidf_(a2);
}

extern "C" void kernel_launch(void* const* d_in, const int* in_sizes, int n_in,
                              void* d_out, int out_size, void* d_ws, size_t ws_size,
                              hipStream_t stream) {
    const float* in   = (const float*)d_in[0];   // [3,1024,1024]
    const float* cw   = (const float*)d_in[1];   // [3,3,5,5]
    const float* cb   = (const float*)d_in[2];   // [3]
    const float* keys = (const float*)d_in[3];   // [100,3072]
    const float* vals = (const float*)d_in[4];   // [100,225]
    float* out = (float*)d_out;                  // [3,128,128] fp32
    float* ws  = (float*)d_ws;
    float* key1   = ws;             // 3072
    float* logit1 = ws + 3072;      // 100
    float* kern1  = ws + 3200;      // 225
    float* w_eff  = ws + 3456;      // 225
    float* key2   = ws + 4096;      // 3072
    float* logit2 = ws + 7168;      // 100
    float* kern2  = ws + 7296;      // 225
    float* comp   = ws + 8192;      // 1801 (W 1521 | pad | Wy | Wx | Wxy)

    k_key   <<<256, 256, 0, stream>>>(in, cw, cb, key1, 510, 1);
    k_logits<<<100, 256, 0, stream>>>(key1, keys, logit1);
    k_mix   <<<1,   256, 0, stream>>>(logit1, vals, cw, kern1, kern1, w_eff, comp, 1);
    k_key   <<<256, 256, 0, stream>>>(in, w_eff, cb, key2, 1022, 0);
    k_logits<<<100, 256, 0, stream>>>(key2, keys, logit2);
    k_mix   <<<1,   256, 0, stream>>>(logit2, vals, cw, kern1, kern2, w_eff, comp, 2);
    k_final <<<128, 128, 0, stream>>>(in, comp, out);
}